// Round 5
// baseline (83.443 us; speedup 1.0000x reference)
//
#include <hip/hip_runtime.h>
#include <math.h>

#define DHID   784
#define HID    1024
#define NB     10
#define MC_LD  800                         // padded leading dim for Mc rows
#define M2_OFF (11*MC_LD)                  // 8800
#define M2_LD  13
#define C0_OFF (M2_OFF + 64*M2_LD)         // 9632
#define WS_FLOATS 9648
#define DELTA0 7.0f

// ---------------------------------------------------------------------------
// ROUND 5: attribution + fix.
// Launches: prep, main_C (round-3 main, unchanged), main_new x3.
//   dur5 - 38.03 = 3 * main_new   (ovh + prep + main_C == round-3 dur)
// main_new: LDS-staged Mc (no L1 broadcast-return cost), R=2 row tiling,
// 512 blocks (2 blk/CU, 8 waves/CU), 1-deep x prefetch.
// ---------------------------------------------------------------------------

// prep: fold all weights. ws layout (floats):
//   [0 .. 8800)   Mc[11][800]: c<10 -> col c of M1 = W_in @ (g .* W_out)
//                              c==10 -> w_mean[d] = (1/1024) * sum_j W_in[d][j]
//   [8800..9632)  M2[64][13] : M2[h][c] = sum_j W_ph[h][j]*g[j]*W_out[j][c]
//   [9632..9642)  c0[10] = (b_in+b_ph)*g @ W_out + b_out
//   [9642]        bmean = mean(b_in)
// g[j] = 2 if j<5 else 1 (spiking gains provably constant).
__global__ __launch_bounds__(256) void prep_kernel(
    const float* __restrict__ W_in,  const float* __restrict__ b_in,
    const float* __restrict__ W_ph,  const float* __restrict__ b_ph,
    const float* __restrict__ W_out, const float* __restrict__ b_out,
    float* __restrict__ ws) {
  __shared__ float wlds[HID * 11];           // 44 KB
  const int tid = threadIdx.x;

  for (int idx = tid; idx < HID * NB; idx += 256) {
    const int j = idx / NB;
    const int c = idx - j * NB;
    wlds[j * 11 + c] = W_out[idx];
  }
  __syncthreads();

  const int w = tid >> 6;
  const int l = tid & 63;
  const int b = blockIdx.x * 4 + w;
  if (b > DHID + 64) return;

  float acc[11];
#pragma unroll
  for (int c = 0; c < 11; ++c) acc[c] = 0.f;

#pragma unroll 4
  for (int it = 0; it < 16; ++it) {
    const int j = l + 64 * it;
    float wv, extra;
    if (b < DHID)           { wv = W_in[b * HID + j];          extra = wv;      }
    else if (b < DHID + 64) { wv = W_ph[(b - DHID) * HID + j]; extra = 0.f;     }
    else                    { wv = b_in[j] + b_ph[j];          extra = b_in[j]; }
    const float wg = (j < 5) ? 2.0f * wv : wv;
    const float* wr = &wlds[j * 11];
#pragma unroll
    for (int c = 0; c < 10; ++c) acc[c] += wg * wr[c];
    acc[10] += extra;
  }

#pragma unroll
  for (int c = 0; c < 11; ++c) {
    float v = acc[c];
    v += __shfl_xor(v, 1,  64);
    v += __shfl_xor(v, 2,  64);
    v += __shfl_xor(v, 4,  64);
    v += __shfl_xor(v, 8,  64);
    v += __shfl_xor(v, 16, 64);
    v += __shfl_xor(v, 32, 64);
    acc[c] = v;
  }

  if (l == 0) {
    if (b < DHID) {
#pragma unroll
      for (int c = 0; c < 10; ++c) ws[c * MC_LD + b] = acc[c];
      ws[10 * MC_LD + b] = acc[10] * (1.0f / HID);
    } else if (b < DHID + 64) {
      const int h = b - DHID;
#pragma unroll
      for (int c = 0; c < 10; ++c) ws[M2_OFF + h * M2_LD + c] = acc[c];
      ws[M2_OFF + h * M2_LD + 10] = 0.f;
      ws[M2_OFF + h * M2_LD + 11] = 0.f;
      ws[M2_OFF + h * M2_LD + 12] = 0.f;
    } else {
#pragma unroll
      for (int c = 0; c < 10; ++c) ws[C0_OFF + c] = acc[c] + b_out[c];
      ws[C0_OFF + 10] = acc[10] * (1.0f / HID);
    }
  }
}

// ---- shared phasor tail ----------------------------------------------------
__device__ __forceinline__ void row_tail_g(int row, const float* a,
                                           const float* m2base, float c0_0_9[],
                                           float* out, int kl) {
  // m2base points at M2 (either ws or lds copy); c0 passed separately.
  const float base = DELTA0 * a[10];      // a[10] already includes bmean
  float s1, c1, s2, c2;
  __sincosf((float)(kl + 1)  * base, &s1, &c1);
  __sincosf((float)(kl + 17) * base, &s2, &c2);
  const float* m2a = m2base + (kl)      * M2_LD;
  const float* m2b = m2base + (kl + 16) * M2_LD;
  const float* m2c = m2base + (kl + 32) * M2_LD;
  const float* m2d = m2base + (kl + 48) * M2_LD;
  float t[10];
#pragma unroll
  for (int c = 0; c < 10; ++c)
    t[c] = c1 * m2a[c] + c2 * m2b[c] + s1 * m2c[c] + s2 * m2d[c];
#pragma unroll
  for (int c = 0; c < 10; ++c) {
    float v = t[c];
    v += __shfl_xor(v, 1, 64);
    v += __shfl_xor(v, 2, 64);
    v += __shfl_xor(v, 4, 64);
    v += __shfl_xor(v, 8, 64);
    t[c] = v;
  }
  if (kl == 0) {
#pragma unroll
    for (int c = 0; c < 10; ++c)
      out[row * NB + c] = a[c] + t[c] + c0_0_9[c];
  }
}

// ---- main_C: round-3 main, unchanged (known-sum anchor) --------------------
__global__ __launch_bounds__(256) void main_kernel_C(const float* __restrict__ x,
                                                     const float* __restrict__ ws,
                                                     float* __restrict__ out) {
  const int tid  = threadIdx.x;
  const int wav  = tid >> 6;
  const int lane = tid & 63;
  const int kl   = lane & 15;
  const int row  = blockIdx.x * 16 + wav * 4 + (lane >> 4);
  const float* x0 = x + (size_t)row * DHID;

  float acc[11];
#pragma unroll
  for (int c = 0; c < 11; ++c) acc[c] = 0.f;

#pragma unroll 2
  for (int i = 0; i < 12; ++i) {
    const int d = 4 * kl + 64 * i;
    const float4 xv = *(const float4*)(x0 + d);
#pragma unroll
    for (int c = 0; c < 11; ++c) {
      const float4 mv = *(const float4*)(ws + c * MC_LD + d);
      acc[c] += xv.x * mv.x + xv.y * mv.y + xv.z * mv.z + xv.w * mv.w;
    }
  }
  if (kl < 4) {
    const int d = 768 + 4 * kl;
    const float4 xv = *(const float4*)(x0 + d);
#pragma unroll
    for (int c = 0; c < 11; ++c) {
      const float4 mv = *(const float4*)(ws + c * MC_LD + d);
      acc[c] += xv.x * mv.x + xv.y * mv.y + xv.z * mv.z + xv.w * mv.w;
    }
  }

#pragma unroll
  for (int c = 0; c < 11; ++c) {
    float v = acc[c];
    v += __shfl_xor(v, 1, 64);
    v += __shfl_xor(v, 2, 64);
    v += __shfl_xor(v, 4, 64);
    v += __shfl_xor(v, 8, 64);
    acc[c] = v;
  }

  float c0loc[10];
#pragma unroll
  for (int c = 0; c < 10; ++c) c0loc[c] = ws[C0_OFF + c];
  float a2[11];
#pragma unroll
  for (int c = 0; c < 10; ++c) a2[c] = acc[c];
  a2[10] = acc[10] + ws[C0_OFF + 10];
  row_tail_g(row, a2, ws + M2_OFF, c0loc, out, kl);
}

// ---- main_new: LDS Mc + R=2 + 512 blocks + 1-deep x prefetch ---------------
__global__ __launch_bounds__(256) void main_kernel_N(const float* __restrict__ x,
                                                     const float* __restrict__ ws,
                                                     float* __restrict__ out) {
  __shared__ float lds[WS_FLOATS];
  const int tid = threadIdx.x;

  for (int idx = tid; idx < WS_FLOATS / 4; idx += 256)
    ((float4*)lds)[idx] = ((const float4*)ws)[idx];
  __syncthreads();

  const int wav  = tid >> 6;
  const int lane = tid & 63;
  const int kl   = lane & 15;
  const int rsub = lane >> 4;
  const int row  = blockIdx.x * 32 + wav * 8 + rsub * 2;   // 2 rows per lane
  const float* x0 = x + (size_t)row * DHID;
  const int d0 = 4 * kl;

  float a0[11], a1[11];
#pragma unroll
  for (int c = 0; c < 11; ++c) { a0[c] = 0.f; a1[c] = 0.f; }

  float4 xa = *(const float4*)(x0 + d0);
  float4 xb = *(const float4*)(x0 + DHID + d0);

  for (int i = 0; i < 12; ++i) {
    float4 na, nb;
    if (i < 11) {                       // prefetch next iteration's x
      const int dn = d0 + 64 * (i + 1);
      na = *(const float4*)(x0 + dn);
      nb = *(const float4*)(x0 + DHID + dn);
    }
    const int d = d0 + 64 * i;
#pragma unroll
    for (int c = 0; c < 11; ++c) {
      const float4 mv = *(const float4*)(&lds[c * MC_LD + d]);
      a0[c] += xa.x * mv.x + xa.y * mv.y + xa.z * mv.z + xa.w * mv.w;
      a1[c] += xb.x * mv.x + xb.y * mv.y + xb.z * mv.z + xb.w * mv.w;
    }
    xa = na; xb = nb;
  }
  if (kl < 4) {                          // tail d = 768+4kl
    const int d = 768 + 4 * kl;
    const float4 ta = *(const float4*)(x0 + d);
    const float4 tb = *(const float4*)(x0 + DHID + d);
#pragma unroll
    for (int c = 0; c < 11; ++c) {
      const float4 mv = *(const float4*)(&lds[c * MC_LD + d]);
      a0[c] += ta.x * mv.x + ta.y * mv.y + ta.z * mv.z + ta.w * mv.w;
      a1[c] += tb.x * mv.x + tb.y * mv.y + tb.z * mv.z + tb.w * mv.w;
    }
  }

#pragma unroll
  for (int c = 0; c < 11; ++c) {
    float v;
    v = a0[c]; v += __shfl_xor(v,1,64); v += __shfl_xor(v,2,64);
    v += __shfl_xor(v,4,64); v += __shfl_xor(v,8,64); a0[c] = v;
    v = a1[c]; v += __shfl_xor(v,1,64); v += __shfl_xor(v,2,64);
    v += __shfl_xor(v,4,64); v += __shfl_xor(v,8,64); a1[c] = v;
  }

  float c0loc[10];
#pragma unroll
  for (int c = 0; c < 10; ++c) c0loc[c] = lds[C0_OFF + c];
  const float bmean = lds[C0_OFF + 10];
  a0[10] += bmean; a1[10] += bmean;
  row_tail_g(row,     a0, &lds[M2_OFF], c0loc, out, kl);
  row_tail_g(row + 1, a1, &lds[M2_OFF], c0loc, out, kl);
}

// ---------------------------------------------------------------------------
extern "C" void kernel_launch(void* const* d_in, const int* in_sizes, int n_in,
                              void* d_out, int out_size, void* d_ws, size_t ws_size,
                              hipStream_t stream) {
  const float* x     = (const float*)d_in[0];
  const float* W_in  = (const float*)d_in[1];
  const float* b_in  = (const float*)d_in[2];
  const float* W_ph  = (const float*)d_in[3];
  const float* b_ph  = (const float*)d_in[4];
  const float* W_out = (const float*)d_in[5];
  const float* b_out = (const float*)d_in[6];
  float* out = (float*)d_out;
  float* ws  = (float*)d_ws;

  // dur5 = ovh + prep + main_C + 3*main_new ; (ovh+prep+main_C) == 38.03 (R3)
  prep_kernel<<<(DHID + 64 + 1 + 3) / 4, 256, 0, stream>>>(W_in, b_in, W_ph, b_ph,
                                                           W_out, b_out, ws);
  main_kernel_C<<<1024, 256, 0, stream>>>(x, ws, out);
  main_kernel_N<<<512, 256, 0, stream>>>(x, ws, out);
  main_kernel_N<<<512, 256, 0, stream>>>(x, ws, out);
  main_kernel_N<<<512, 256, 0, stream>>>(x, ws, out);
}